// Round 1
// baseline (1325.944 us; speedup 1.0000x reference)
//
#include <hip/hip_runtime.h>

#define C 128
#define NT 16  // nodes per combine block

// ---------------- Kernel 1: embedding-bag sum + LayerNorm + ReLU ----------------
// one wave (64 lanes) per node; each lane owns 2 channels (float2)
__global__ __launch_bounds__(256) void k_embed_ln(
    const int* __restrict__ x, const float* __restrict__ emb,
    const float* __restrict__ g, const float* __restrict__ b,
    float* __restrict__ h, int n0) {
  unsigned gid = blockIdx.x * blockDim.x + threadIdx.x;
  int node = gid >> 6;
  int lane = threadIdx.x & 63;
  if (node >= n0) return;
  const int* xr = x + (size_t)node * 16;
  float sx = 0.f, sy = 0.f;
#pragma unroll
  for (int w = 0; w < 16; ++w) {
    int t = xr[w];
    float2 v = ((const float2*)(emb + (size_t)t * C))[lane];
    sx += v.x; sy += v.y;
  }
  // mean across 128 channels
  float red = sx + sy;
#pragma unroll
  for (int off = 32; off; off >>= 1) red += __shfl_xor(red, off, 64);
  float mu = red * (1.f / C);
  float cx = sx - mu, cy = sy - mu;
  float sq = cx * cx + cy * cy;
#pragma unroll
  for (int off = 32; off; off >>= 1) sq += __shfl_xor(sq, off, 64);
  float rs = rsqrtf(sq * (1.f / C) + 1e-5f);
  float2 gg = ((const float2*)g)[lane];
  float2 bb = ((const float2*)b)[lane];
  float2 o;
  o.x = fmaxf(cx * rs * gg.x + bb.x, 0.f);
  o.y = fmaxf(cy * rs * gg.y + bb.y, 0.f);
  ((float2*)(h + (size_t)node * C))[lane] = o;
}

// ---------------- Kernel 2/4: per-edge gather + atomic scatter ----------------
// 32 threads per edge; each thread moves 4 channels (float4 read, 4 atomic adds)
__global__ __launch_bounds__(256) void k_scatter(
    const int* __restrict__ src, const int* __restrict__ dst,
    const float* __restrict__ h, float* __restrict__ agg,
    float* __restrict__ cnt, int ne) {
  unsigned gid = blockIdx.x * blockDim.x + threadIdx.x;
  int e = gid >> 5;
  int p = gid & 31;
  if (e >= ne) return;
  int s = src[e], d = dst[e];
  float4 v = ((const float4*)(h + (size_t)s * C))[p];
  float* a = agg + (size_t)d * C + p * 4;
  atomicAdd(a + 0, v.x);
  atomicAdd(a + 1, v.y);
  atomicAdd(a + 2, v.z);
  atomicAdd(a + 3, v.w);
  if (p == 0) atomicAdd(cnt + d, 1.f);
}

// ---------------- Kernel 3/5: combine ----------------
// out[i] = (agg[i]/max(cnt,1)) @ Wl^T + bl + hsrc[i] @ Wr^T   (+ optional ReLU)
// block = 256 threads handles NT=16 nodes; inputs staged in LDS (broadcast reads);
// thread (c, half) computes channel c for 8 nodes.
template <bool RELU>
__global__ __launch_bounds__(256) void k_combine(
    const float* __restrict__ agg, const float* __restrict__ cnt,
    const float* __restrict__ hsrc, const float* __restrict__ Wl,
    const float* __restrict__ bl, const float* __restrict__ Wr,
    float* __restrict__ out, int ntgt) {
  __shared__ float4 s_mean[NT * 32];
  __shared__ float4 s_h[NT * 32];
  int nb = blockIdx.x * NT;
  int t = threadIdx.x;
  for (int i = t; i < NT * 32; i += 256) {
    int row = i >> 5;
    int node = nb + row;
    float4 m = {0.f, 0.f, 0.f, 0.f}, hh = {0.f, 0.f, 0.f, 0.f};
    if (node < ntgt) {
      float sc = 1.f / fmaxf(cnt[node], 1.f);
      float4 a = ((const float4*)agg)[(size_t)node * 32 + (i & 31)];
      m.x = a.x * sc; m.y = a.y * sc; m.z = a.z * sc; m.w = a.w * sc;
      hh = ((const float4*)hsrc)[(size_t)node * 32 + (i & 31)];
    }
    s_mean[i] = m;
    s_h[i] = hh;
  }
  __syncthreads();
  int c = t & 127;
  int half = t >> 7;
  const float4* wl4 = (const float4*)(Wl + (size_t)c * C);
  const float4* wr4 = (const float4*)(Wr + (size_t)c * C);
  float acc[8] = {0.f, 0.f, 0.f, 0.f, 0.f, 0.f, 0.f, 0.f};
#pragma unroll 4
  for (int k = 0; k < 32; ++k) {
    float4 wl = wl4[k];
    float4 wr = wr4[k];
#pragma unroll
    for (int j = 0; j < 8; ++j) {
      int r = half * 8 + j;
      float4 m = s_mean[r * 32 + k];
      float4 hh = s_h[r * 32 + k];
      acc[j] += wl.x * m.x + wl.y * m.y + wl.z * m.z + wl.w * m.w
              + wr.x * hh.x + wr.y * hh.y + wr.z * hh.z + wr.w * hh.w;
    }
  }
  float bias = bl[c];
#pragma unroll
  for (int j = 0; j < 8; ++j) {
    int node = nb + half * 8 + j;
    if (node < ntgt) {
      float v = acc[j] + bias;
      if (RELU) v = fmaxf(v, 0.f);
      out[(size_t)node * C + c] = v;
    }
  }
}

extern "C" void kernel_launch(void* const* d_in, const int* in_sizes, int n_in,
                              void* d_out, int out_size, void* d_ws, size_t ws_size,
                              hipStream_t stream) {
  const int*   x    = (const int*)d_in[0];
  const int*   src1 = (const int*)d_in[1];
  const int*   dst1 = (const int*)d_in[2];
  const int*   src2 = (const int*)d_in[3];
  const int*   dst2 = (const int*)d_in[4];
  // d_in[5]=n1, d_in[6]=n2 (device scalars; values fixed by problem spec)
  const float* emb  = (const float*)d_in[7];
  const float* ln_g = (const float*)d_in[8];
  const float* ln_b = (const float*)d_in[9];
  const float* Wl1  = (const float*)d_in[10];
  const float* bl1  = (const float*)d_in[11];
  const float* Wr1  = (const float*)d_in[12];
  const float* Wl2  = (const float*)d_in[13];
  const float* bl2  = (const float*)d_in[14];
  const float* Wr2  = (const float*)d_in[15];

  const int N0 = in_sizes[0] / 16;   // 100000
  const int E1 = in_sizes[1];        // 500000
  const int E2 = in_sizes[3];        // 100000
  const int N1 = 25000;
  const int N2 = 5000;

  // workspace layout (bytes), all 256-aligned
  char* ws = (char*)d_ws;
  size_t off = 0;
  float* h0   = (float*)(ws + off); off += (size_t)N0 * C * 4;           // 51.2 MB
  char*  zb   = ws + off;           size_t z0 = off;                      // zero region start
  float* agg1 = (float*)(ws + off); off += (size_t)N1 * C * 4;           // 12.8 MB
  float* cnt1 = (float*)(ws + off); off += ((size_t)N1 * 4 + 255) & ~(size_t)255;
  float* agg2 = (float*)(ws + off); off += (size_t)N2 * C * 4;           // 2.56 MB
  float* cnt2 = (float*)(ws + off); off += ((size_t)N2 * 4 + 255) & ~(size_t)255;
  size_t zbytes = off - z0;
  float* h1   = (float*)(ws + off); off += (size_t)N1 * C * 4;           // 12.8 MB

  float* out = (float*)d_out;

  // zero the accumulators (ws is poisoned 0xAA before every call)
  hipMemsetAsync(zb, 0, zbytes, stream);

  // 1) embedding-bag + LN + ReLU -> h0 [N0, 128]
  {
    int waves_per_block = 4;
    int blocks = (N0 + waves_per_block - 1) / waves_per_block;
    k_embed_ln<<<blocks, 256, 0, stream>>>(x, emb, ln_g, ln_b, h0, N0);
  }
  // 2) conv1 aggregate
  {
    unsigned threads = (unsigned)E1 * 32u;
    k_scatter<<<(threads + 255) / 256, 256, 0, stream>>>(src1, dst1, h0, agg1, cnt1, E1);
  }
  // 3) conv1 combine + ReLU -> h1 [N1, 128]
  k_combine<true><<<(N1 + NT - 1) / NT, 256, 0, stream>>>(agg1, cnt1, h0, Wl1, bl1, Wr1, h1, N1);
  // 4) conv2 aggregate
  {
    unsigned threads = (unsigned)E2 * 32u;
    k_scatter<<<(threads + 255) / 256, 256, 0, stream>>>(src2, dst2, h1, agg2, cnt2, E2);
  }
  // 5) conv2 combine (no ReLU) -> d_out [N2, 128]
  k_combine<false><<<(N2 + NT - 1) / NT, 256, 0, stream>>>(agg2, cnt2, h1, Wl2, bl2, Wr2, out, N2);
}

// Round 2
// 446.764 us; speedup vs baseline: 2.9679x; 2.9679x over previous
//
#include <hip/hip_runtime.h>

#define C 128
#define NT 16  // nodes per combine block

// ---------------- Kernel 1: embedding-bag sum + LayerNorm + ReLU ----------------
// one wave (64 lanes) per node; each lane owns 2 channels (float2)
__global__ __launch_bounds__(256) void k_embed_ln(
    const int* __restrict__ x, const float* __restrict__ emb,
    const float* __restrict__ g, const float* __restrict__ b,
    float* __restrict__ h, int n0) {
  unsigned gid = blockIdx.x * blockDim.x + threadIdx.x;
  int node = gid >> 6;
  int lane = threadIdx.x & 63;
  if (node >= n0) return;
  const int* xr = x + (size_t)node * 16;
  float sx = 0.f, sy = 0.f;
#pragma unroll
  for (int w = 0; w < 16; ++w) {
    int t = xr[w];
    float2 v = ((const float2*)(emb + (size_t)t * C))[lane];
    sx += v.x; sy += v.y;
  }
  float red = sx + sy;
#pragma unroll
  for (int off = 32; off; off >>= 1) red += __shfl_xor(red, off, 64);
  float mu = red * (1.f / C);
  float cx = sx - mu, cy = sy - mu;
  float sq = cx * cx + cy * cy;
#pragma unroll
  for (int off = 32; off; off >>= 1) sq += __shfl_xor(sq, off, 64);
  float rs = rsqrtf(sq * (1.f / C) + 1e-5f);
  float2 gg = ((const float2*)g)[lane];
  float2 bb = ((const float2*)b)[lane];
  float2 o;
  o.x = fmaxf(cx * rs * gg.x + bb.x, 0.f);
  o.y = fmaxf(cy * rs * gg.y + bb.y, 0.f);
  ((float2*)(h + (size_t)node * C))[lane] = o;
}

// ---------------- CSR build: histogram ----------------
__global__ __launch_bounds__(256) void k_hist(
    const int* __restrict__ dst, int* __restrict__ deg, int ne) {
  int i = blockIdx.x * blockDim.x + threadIdx.x;
  if (i < ne) atomicAdd(&deg[dst[i]], 1);
}

// ---------------- CSR build: single-block exclusive scan ----------------
__global__ __launch_bounds__(1024) void k_scan(
    const int* __restrict__ deg, int* __restrict__ rowptr, int n) {
  __shared__ int part[1024];
  int t = threadIdx.x;
  int chunk = (n + 1023) >> 10;
  int lo = t * chunk;
  int hi = min(lo + chunk, n);
  int s = 0;
  for (int i = lo; i < hi; ++i) s += deg[i];
  part[t] = s;
  __syncthreads();
  for (int off = 1; off < 1024; off <<= 1) {
    int v = (t >= off) ? part[t - off] : 0;
    __syncthreads();
    part[t] += v;
    __syncthreads();
  }
  int run = (t == 0) ? 0 : part[t - 1];
  for (int i = lo; i < hi; ++i) {
    rowptr[i] = run;
    run += deg[i];
  }
}

// ---------------- CSR build: bucket src ids ----------------
__global__ __launch_bounds__(256) void k_bucket(
    const int* __restrict__ src, const int* __restrict__ dst,
    const int* __restrict__ rowptr, int* __restrict__ cursor,
    int* __restrict__ eidx, int ne) {
  int i = blockIdx.x * blockDim.x + threadIdx.x;
  if (i >= ne) return;
  int d = dst[i];
  int pos = rowptr[d] + atomicAdd(&cursor[d], 1);
  eidx[pos] = src[i];
}

// ---------------- Aggregate: one wave per dst node, mean of h[src] ----------------
__global__ __launch_bounds__(256) void k_aggregate(
    const int* __restrict__ rowptr, const int* __restrict__ deg,
    const int* __restrict__ eidx, const float* __restrict__ h,
    float* __restrict__ mean, int ntgt) {
  unsigned gid = blockIdx.x * blockDim.x + threadIdx.x;
  int node = gid >> 6;
  int lane = threadIdx.x & 63;
  if (node >= ntgt) return;
  int row = rowptr[node];
  int dg = deg[node];
  float sx = 0.f, sy = 0.f;
  for (int j0 = 0; j0 < dg; j0 += 64) {
    int idx = j0 + lane;
    int e = (idx < dg) ? eidx[row + idx] : 0;
    int cnt = min(64, dg - j0);
    for (int d = 0; d < cnt; ++d) {
      int s = __shfl(e, d, 64);
      float2 v = ((const float2*)(h + (size_t)s * C))[lane];
      sx += v.x;
      sy += v.y;
    }
  }
  float sc = 1.f / (float)max(dg, 1);
  float2 o;
  o.x = sx * sc;
  o.y = sy * sc;
  ((float2*)(mean + (size_t)node * C))[lane] = o;
}

// ---------------- Combine: out = mean @ Wl^T + bl + hsrc @ Wr^T (+ReLU) ----------------
template <bool RELU>
__global__ __launch_bounds__(256) void k_combine(
    const float* __restrict__ mean, const float* __restrict__ hsrc,
    const float* __restrict__ Wl, const float* __restrict__ bl,
    const float* __restrict__ Wr, float* __restrict__ out, int ntgt) {
  __shared__ float4 s_mean[NT * 32];
  __shared__ float4 s_h[NT * 32];
  int nb = blockIdx.x * NT;
  int t = threadIdx.x;
  for (int i = t; i < NT * 32; i += 256) {
    int row = i >> 5;
    int node = nb + row;
    float4 m = {0.f, 0.f, 0.f, 0.f}, hh = {0.f, 0.f, 0.f, 0.f};
    if (node < ntgt) {
      m = ((const float4*)mean)[(size_t)node * 32 + (i & 31)];
      hh = ((const float4*)hsrc)[(size_t)node * 32 + (i & 31)];
    }
    s_mean[i] = m;
    s_h[i] = hh;
  }
  __syncthreads();
  int c = t & 127;
  int half = t >> 7;
  const float4* wl4 = (const float4*)(Wl + (size_t)c * C);
  const float4* wr4 = (const float4*)(Wr + (size_t)c * C);
  float acc[8] = {0.f, 0.f, 0.f, 0.f, 0.f, 0.f, 0.f, 0.f};
#pragma unroll 4
  for (int k = 0; k < 32; ++k) {
    float4 wl = wl4[k];
    float4 wr = wr4[k];
#pragma unroll
    for (int j = 0; j < 8; ++j) {
      int r = half * 8 + j;
      float4 m = s_mean[r * 32 + k];
      float4 hh = s_h[r * 32 + k];
      acc[j] += wl.x * m.x + wl.y * m.y + wl.z * m.z + wl.w * m.w
              + wr.x * hh.x + wr.y * hh.y + wr.z * hh.z + wr.w * hh.w;
    }
  }
  float bias = bl[c];
#pragma unroll
  for (int j = 0; j < 8; ++j) {
    int node = nb + half * 8 + j;
    if (node < ntgt) {
      float v = acc[j] + bias;
      if (RELU) v = fmaxf(v, 0.f);
      out[(size_t)node * C + c] = v;
    }
  }
}

extern "C" void kernel_launch(void* const* d_in, const int* in_sizes, int n_in,
                              void* d_out, int out_size, void* d_ws, size_t ws_size,
                              hipStream_t stream) {
  const int*   x    = (const int*)d_in[0];
  const int*   src1 = (const int*)d_in[1];
  const int*   dst1 = (const int*)d_in[2];
  const int*   src2 = (const int*)d_in[3];
  const int*   dst2 = (const int*)d_in[4];
  const float* emb  = (const float*)d_in[7];
  const float* ln_g = (const float*)d_in[8];
  const float* ln_b = (const float*)d_in[9];
  const float* Wl1  = (const float*)d_in[10];
  const float* bl1  = (const float*)d_in[11];
  const float* Wr1  = (const float*)d_in[12];
  const float* Wl2  = (const float*)d_in[13];
  const float* bl2  = (const float*)d_in[14];
  const float* Wr2  = (const float*)d_in[15];

  const int N0 = in_sizes[0] / 16;   // 100000
  const int E1 = in_sizes[1];        // 500000
  const int E2 = in_sizes[3];        // 100000
  const int N1 = 25000;
  const int N2 = 5000;

  // workspace layout (bytes), 256-aligned chunks
  char* ws = (char*)d_ws;
  size_t off = 0;
  auto alloc = [&](size_t bytes) {
    char* p = ws + off;
    off += (bytes + 255) & ~(size_t)255;
    return p;
  };
  float* h0    = (float*)alloc((size_t)N0 * C * 4);  // 51.2 MB
  float* h1    = (float*)alloc((size_t)N1 * C * 4);  // 12.8 MB
  float* mean1 = (float*)alloc((size_t)N1 * C * 4);  // 12.8 MB
  float* mean2 = (float*)alloc((size_t)N2 * C * 4);  //  2.56 MB
  int*   eidx1 = (int*)alloc((size_t)E1 * 4);        //  2 MB
  int*   eidx2 = (int*)alloc((size_t)E2 * 4);        //  0.4 MB
  // small zeroed region: deg1, cursor1, deg2, cursor2 (contiguous)
  char*  zbase = ws + off;
  int*   deg1    = (int*)alloc((size_t)N1 * 4);
  int*   cursor1 = (int*)alloc((size_t)N1 * 4);
  int*   deg2    = (int*)alloc((size_t)N2 * 4);
  int*   cursor2 = (int*)alloc((size_t)N2 * 4);
  size_t zbytes = (size_t)((ws + off) - zbase);
  int*   rowptr1 = (int*)alloc((size_t)N1 * 4);
  int*   rowptr2 = (int*)alloc((size_t)N2 * 4);

  float* out = (float*)d_out;

  hipMemsetAsync(zbase, 0, zbytes, stream);

  // 1) embedding-bag + LN + ReLU -> h0 [N0, 128]
  k_embed_ln<<<(N0 + 3) / 4, 256, 0, stream>>>(x, emb, ln_g, ln_b, h0, N0);

  // 2) conv1: CSR build + aggregate + combine
  k_hist<<<(E1 + 255) / 256, 256, 0, stream>>>(dst1, deg1, E1);
  k_scan<<<1, 1024, 0, stream>>>(deg1, rowptr1, N1);
  k_bucket<<<(E1 + 255) / 256, 256, 0, stream>>>(src1, dst1, rowptr1, cursor1, eidx1, E1);
  k_aggregate<<<(N1 + 3) / 4, 256, 0, stream>>>(rowptr1, deg1, eidx1, h0, mean1, N1);
  k_combine<true><<<(N1 + NT - 1) / NT, 256, 0, stream>>>(mean1, h0, Wl1, bl1, Wr1, h1, N1);

  // 3) conv2: CSR build + aggregate + combine
  k_hist<<<(E2 + 255) / 256, 256, 0, stream>>>(dst2, deg2, E2);
  k_scan<<<1, 1024, 0, stream>>>(deg2, rowptr2, N2);
  k_bucket<<<(E2 + 255) / 256, 256, 0, stream>>>(src2, dst2, rowptr2, cursor2, eidx2, E2);
  k_aggregate<<<(N2 + 3) / 4, 256, 0, stream>>>(rowptr2, deg2, eidx2, h1, mean2, N2);
  k_combine<false><<<(N2 + NT - 1) / NT, 256, 0, stream>>>(mean2, h1, Wl2, bl2, Wr2, out, N2);
}

// Round 3
// 351.912 us; speedup vs baseline: 3.7678x; 1.2695x over previous
//
#include <hip/hip_runtime.h>

#define C 128
#define NT 16  // nodes per combine block

typedef unsigned int uint;
typedef unsigned short ushort;

__device__ __forceinline__ float bf_lo(uint u) { return __uint_as_float(u << 16); }
__device__ __forceinline__ float bf_hi(uint u) { return __uint_as_float(u & 0xffff0000u); }
__device__ __forceinline__ uint f2bf(float f) {
  uint u = __float_as_uint(f);
  return (u + 0x7fffu + ((u >> 16) & 1u)) >> 16;  // RNE, no NaN inputs
}
__device__ __forceinline__ uint pack2(float a, float b) { return f2bf(a) | (f2bf(b) << 16); }

// ---------------- Kernel 0: fp32 -> bf16 table convert ----------------
__global__ __launch_bounds__(256) void k_cvt(
    const float4* __restrict__ in, ushort4* __restrict__ out, int n4) {
  int i = blockIdx.x * blockDim.x + threadIdx.x;
  if (i >= n4) return;
  float4 f = in[i];
  ushort4 o;
  o.x = (ushort)f2bf(f.x);
  o.y = (ushort)f2bf(f.y);
  o.z = (ushort)f2bf(f.z);
  o.w = (ushort)f2bf(f.w);
  out[i] = o;
}

// ---------------- Kernel 1: embedding-bag sum + LayerNorm + ReLU (bf16 in/out) ----------------
// one wave per node; lane owns channels {2*lane, 2*lane+1}
__global__ __launch_bounds__(256) void k_embed_ln(
    const int* __restrict__ x, const ushort* __restrict__ emb,
    const float* __restrict__ g, const float* __restrict__ b,
    ushort* __restrict__ h, int n0) {
  unsigned gid = blockIdx.x * blockDim.x + threadIdx.x;
  int node = gid >> 6;
  int lane = threadIdx.x & 63;
  if (node >= n0) return;
  const int* xr = x + (size_t)node * 16;
  float sx = 0.f, sy = 0.f;
#pragma unroll
  for (int w = 0; w < 16; ++w) {
    int t = xr[w];
    uint u = ((const uint*)(emb + (size_t)t * C))[lane];
    sx += bf_lo(u);
    sy += bf_hi(u);
  }
  float red = sx + sy;
#pragma unroll
  for (int off = 32; off; off >>= 1) red += __shfl_xor(red, off, 64);
  float mu = red * (1.f / C);
  float cx = sx - mu, cy = sy - mu;
  float sq = cx * cx + cy * cy;
#pragma unroll
  for (int off = 32; off; off >>= 1) sq += __shfl_xor(sq, off, 64);
  float rs = rsqrtf(sq * (1.f / C) + 1e-5f);
  float2 gg = ((const float2*)g)[lane];
  float2 bb = ((const float2*)b)[lane];
  float ox = fmaxf(cx * rs * gg.x + bb.x, 0.f);
  float oy = fmaxf(cy * rs * gg.y + bb.y, 0.f);
  ((uint*)(h + (size_t)node * C))[lane] = pack2(ox, oy);
}

// ---------------- CSR build: fused histogram over both edge lists ----------------
__global__ __launch_bounds__(256) void k_hist2(
    const int* __restrict__ dst1, int* __restrict__ deg1, int e1,
    const int* __restrict__ dst2, int* __restrict__ deg2, int e2) {
  int i = blockIdx.x * blockDim.x + threadIdx.x;
  if (i < e1) atomicAdd(&deg1[dst1[i]], 1);
  else if (i < e1 + e2) atomicAdd(&deg2[dst2[i - e1]], 1);
}

// ---------------- CSR build: exclusive scan (block 0 -> graph1, block 1 -> graph2) ----------------
// writes rowptr[0..n], rowptr[n] = total
__global__ __launch_bounds__(1024) void k_scan2(
    const int* __restrict__ degA, int* __restrict__ rpA, int nA,
    const int* __restrict__ degB, int* __restrict__ rpB, int nB) {
  const int* deg = blockIdx.x ? degB : degA;
  int* rowptr = blockIdx.x ? rpB : rpA;
  int n = blockIdx.x ? nB : nA;
  __shared__ int part[1024];
  int t = threadIdx.x;
  int chunk = (n + 1023) >> 10;
  int lo = t * chunk;
  int hi = min(lo + chunk, n);
  int s = 0;
  for (int i = lo; i < hi; ++i) s += deg[i];
  part[t] = s;
  __syncthreads();
  for (int off = 1; off < 1024; off <<= 1) {
    int v = (t >= off) ? part[t - off] : 0;
    __syncthreads();
    part[t] += v;
    __syncthreads();
  }
  int run = (t == 0) ? 0 : part[t - 1];
  for (int i = lo; i < hi; ++i) {
    rowptr[i] = run;
    run += deg[i];
  }
  if (t == 1023) rowptr[n] = part[1023];
}

// ---------------- CSR build: fused bucket of src ids ----------------
__global__ __launch_bounds__(256) void k_bucket2(
    const int* __restrict__ src1, const int* __restrict__ dst1,
    const int* __restrict__ rp1, int* __restrict__ cur1,
    int* __restrict__ eidx1, int e1,
    const int* __restrict__ src2, const int* __restrict__ dst2,
    const int* __restrict__ rp2, int* __restrict__ cur2,
    int* __restrict__ eidx2, int e2) {
  int i = blockIdx.x * blockDim.x + threadIdx.x;
  if (i < e1) {
    int d = dst1[i];
    eidx1[rp1[d] + atomicAdd(&cur1[d], 1)] = src1[i];
  } else if (i < e1 + e2) {
    int j = i - e1;
    int d = dst2[j];
    eidx2[rp2[d] + atomicAdd(&cur2[d], 1)] = src2[j];
  }
}

// ---------------- Aggregate: one wave per dst node, mean of bf16 h[src] ----------------
__global__ __launch_bounds__(256) void k_aggregate(
    const int* __restrict__ rowptr, const int* __restrict__ eidx,
    const ushort* __restrict__ h, float* __restrict__ mean, int ntgt) {
  unsigned gid = blockIdx.x * blockDim.x + threadIdx.x;
  int node = gid >> 6;
  int lane = threadIdx.x & 63;
  if (node >= ntgt) return;
  int row = rowptr[node];
  int end = rowptr[node + 1];
  int dg = end - row;
  float sx = 0.f, sy = 0.f;
  for (int j0 = row; j0 < end; j0 += 64) {
    int idx = j0 + lane;
    int e = (idx < end) ? eidx[idx] : 0;
    int cnt = min(64, end - j0);
    int d = 0;
    for (; d + 3 < cnt; d += 4) {  // 4 gathers in flight
      int s0 = __shfl(e, d, 64);
      int s1 = __shfl(e, d + 1, 64);
      int s2 = __shfl(e, d + 2, 64);
      int s3 = __shfl(e, d + 3, 64);
      uint u0 = ((const uint*)(h + (size_t)s0 * C))[lane];
      uint u1 = ((const uint*)(h + (size_t)s1 * C))[lane];
      uint u2 = ((const uint*)(h + (size_t)s2 * C))[lane];
      uint u3 = ((const uint*)(h + (size_t)s3 * C))[lane];
      sx += bf_lo(u0) + bf_lo(u1) + bf_lo(u2) + bf_lo(u3);
      sy += bf_hi(u0) + bf_hi(u1) + bf_hi(u2) + bf_hi(u3);
    }
    for (; d < cnt; ++d) {
      int s0 = __shfl(e, d, 64);
      uint u0 = ((const uint*)(h + (size_t)s0 * C))[lane];
      sx += bf_lo(u0);
      sy += bf_hi(u0);
    }
  }
  float sc = 1.f / (float)max(dg, 1);
  float2 o;
  o.x = sx * sc;
  o.y = sy * sc;
  ((float2*)(mean + (size_t)node * C))[lane] = o;
}

// ---------------- Combine: out = mean @ Wl^T + bl + hsrc @ Wr^T (+ReLU) ----------------
// mean fp32, hsrc bf16; output bf16 (intermediate) or fp32 (final)
template <bool RELU, bool BF16OUT>
__global__ __launch_bounds__(256) void k_combine(
    const float* __restrict__ mean, const ushort* __restrict__ hsrc,
    const float* __restrict__ Wl, const float* __restrict__ bl,
    const float* __restrict__ Wr, void* __restrict__ outp, int ntgt) {
  __shared__ float4 s_mean[NT * 32];
  __shared__ float4 s_h[NT * 32];
  int nb = blockIdx.x * NT;
  int t = threadIdx.x;
  for (int i = t; i < NT * 32; i += 256) {
    int row = i >> 5;
    int node = nb + row;
    float4 m = {0.f, 0.f, 0.f, 0.f}, hh = {0.f, 0.f, 0.f, 0.f};
    if (node < ntgt) {
      m = ((const float4*)mean)[(size_t)node * 32 + (i & 31)];
      uint2 hu = ((const uint2*)(hsrc + (size_t)node * C))[i & 31];
      hh.x = bf_lo(hu.x);
      hh.y = bf_hi(hu.x);
      hh.z = bf_lo(hu.y);
      hh.w = bf_hi(hu.y);
    }
    s_mean[i] = m;
    s_h[i] = hh;
  }
  __syncthreads();
  int c = t & 127;
  int half = t >> 7;
  const float4* wl4 = (const float4*)(Wl + (size_t)c * C);
  const float4* wr4 = (const float4*)(Wr + (size_t)c * C);
  float acc[8] = {0.f, 0.f, 0.f, 0.f, 0.f, 0.f, 0.f, 0.f};
#pragma unroll 4
  for (int k = 0; k < 32; ++k) {
    float4 wl = wl4[k];
    float4 wr = wr4[k];
#pragma unroll
    for (int j = 0; j < 8; ++j) {
      int r = half * 8 + j;
      float4 m = s_mean[r * 32 + k];
      float4 hh = s_h[r * 32 + k];
      acc[j] += wl.x * m.x + wl.y * m.y + wl.z * m.z + wl.w * m.w
              + wr.x * hh.x + wr.y * hh.y + wr.z * hh.z + wr.w * hh.w;
    }
  }
  float bias = bl[c];
#pragma unroll
  for (int j = 0; j < 8; ++j) {
    int node = nb + half * 8 + j;
    if (node < ntgt) {
      float v = acc[j] + bias;
      if (RELU) v = fmaxf(v, 0.f);
      if (BF16OUT)
        ((ushort*)outp)[(size_t)node * C + c] = (ushort)f2bf(v);
      else
        ((float*)outp)[(size_t)node * C + c] = v;
    }
  }
}

extern "C" void kernel_launch(void* const* d_in, const int* in_sizes, int n_in,
                              void* d_out, int out_size, void* d_ws, size_t ws_size,
                              hipStream_t stream) {
  const int*   x    = (const int*)d_in[0];
  const int*   src1 = (const int*)d_in[1];
  const int*   dst1 = (const int*)d_in[2];
  const int*   src2 = (const int*)d_in[3];
  const int*   dst2 = (const int*)d_in[4];
  const float* emb  = (const float*)d_in[7];
  const float* ln_g = (const float*)d_in[8];
  const float* ln_b = (const float*)d_in[9];
  const float* Wl1  = (const float*)d_in[10];
  const float* bl1  = (const float*)d_in[11];
  const float* Wr1  = (const float*)d_in[12];
  const float* Wl2  = (const float*)d_in[13];
  const float* bl2  = (const float*)d_in[14];
  const float* Wr2  = (const float*)d_in[15];

  const int N0 = in_sizes[0] / 16;   // 100000
  const int E1 = in_sizes[1];        // 500000
  const int E2 = in_sizes[3];        // 100000
  const int N1 = 25000;
  const int N2 = 5000;
  const int LEAF_ELEMS = in_sizes[7];  // 50000*128

  char* ws = (char*)d_ws;
  size_t off = 0;
  auto alloc = [&](size_t bytes) {
    char* p = ws + off;
    off += (bytes + 255) & ~(size_t)255;
    return p;
  };
  ushort* embh  = (ushort*)alloc((size_t)LEAF_ELEMS * 2);  // 12.8 MB
  ushort* h0    = (ushort*)alloc((size_t)N0 * C * 2);      // 25.6 MB
  ushort* h1    = (ushort*)alloc((size_t)N1 * C * 2);      //  6.4 MB
  float*  mean1 = (float*)alloc((size_t)N1 * C * 4);       // 12.8 MB
  float*  mean2 = (float*)alloc((size_t)N2 * C * 4);       //  2.56 MB
  int*    eidx1 = (int*)alloc((size_t)E1 * 4);
  int*    eidx2 = (int*)alloc((size_t)E2 * 4);
  char*   zbase = ws + off;
  int*    deg1 = (int*)alloc((size_t)N1 * 4);
  int*    cur1 = (int*)alloc((size_t)N1 * 4);
  int*    deg2 = (int*)alloc((size_t)N2 * 4);
  int*    cur2 = (int*)alloc((size_t)N2 * 4);
  size_t  zbytes = (size_t)((ws + off) - zbase);
  int*    rp1 = (int*)alloc((size_t)(N1 + 1) * 4);
  int*    rp2 = (int*)alloc((size_t)(N2 + 1) * 4);

  float* out = (float*)d_out;

  hipMemsetAsync(zbase, 0, zbytes, stream);

  // 0) convert table to bf16
  k_cvt<<<(LEAF_ELEMS / 4 + 255) / 256, 256, 0, stream>>>(
      (const float4*)emb, (ushort4*)embh, LEAF_ELEMS / 4);

  // 1) embedding-bag + LN + ReLU -> h0 bf16 [N0,128]
  k_embed_ln<<<(N0 + 3) / 4, 256, 0, stream>>>(x, embh, ln_g, ln_b, h0, N0);

  // 2) CSR build (both graphs, fused)
  k_hist2<<<(E1 + E2 + 255) / 256, 256, 0, stream>>>(dst1, deg1, E1, dst2, deg2, E2);
  k_scan2<<<2, 1024, 0, stream>>>(deg1, rp1, N1, deg2, rp2, N2);
  k_bucket2<<<(E1 + E2 + 255) / 256, 256, 0, stream>>>(
      src1, dst1, rp1, cur1, eidx1, E1, src2, dst2, rp2, cur2, eidx2, E2);

  // 3) conv1
  k_aggregate<<<(N1 + 3) / 4, 256, 0, stream>>>(rp1, eidx1, h0, mean1, N1);
  k_combine<true, true><<<(N1 + NT - 1) / NT, 256, 0, stream>>>(
      mean1, h0, Wl1, bl1, Wr1, h1, N1);

  // 4) conv2
  k_aggregate<<<(N2 + 3) / 4, 256, 0, stream>>>(rp2, eidx2, h1, mean2, N2);
  k_combine<false, false><<<(N2 + NT - 1) / NT, 256, 0, stream>>>(
      mean2, h1, Wl2, bl2, Wr2, out, N2);
}

// Round 4
// 303.882 us; speedup vs baseline: 4.3633x; 1.1581x over previous
//
#include <hip/hip_runtime.h>

#define C 128

typedef unsigned int uint;
typedef unsigned short ushort;
typedef __attribute__((ext_vector_type(8))) short bf16x8;
typedef __attribute__((ext_vector_type(4))) float f32x4;

__device__ __forceinline__ float bf_lo(uint u) { return __uint_as_float(u << 16); }
__device__ __forceinline__ float bf_hi(uint u) { return __uint_as_float(u & 0xffff0000u); }
__device__ __forceinline__ uint f2bf(float f) {
  uint u = __float_as_uint(f);
  return (u + 0x7fffu + ((u >> 16) & 1u)) >> 16;  // RNE, no NaN inputs
}
__device__ __forceinline__ uint pack2(float a, float b) { return f2bf(a) | (f2bf(b) << 16); }

// ---------------- fp32 -> bf16 converters ----------------
__global__ __launch_bounds__(256) void k_cvt(
    const float4* __restrict__ in, ushort4* __restrict__ out, int n4) {
  int i = blockIdx.x * blockDim.x + threadIdx.x;
  if (i >= n4) return;
  float4 f = in[i];
  ushort4 o;
  o.x = (ushort)f2bf(f.x);
  o.y = (ushort)f2bf(f.y);
  o.z = (ushort)f2bf(f.z);
  o.w = (ushort)f2bf(f.w);
  out[i] = o;
}

// convert 4 weight matrices (each n4each float4 chunks)
__global__ __launch_bounds__(256) void k_cvt4(
    const float4* __restrict__ a, const float4* __restrict__ b,
    const float4* __restrict__ c, const float4* __restrict__ d,
    ushort4* __restrict__ oa, ushort4* __restrict__ ob,
    ushort4* __restrict__ oc, ushort4* __restrict__ od, int n4each) {
  int i = blockIdx.x * blockDim.x + threadIdx.x;
  int which = i / n4each;
  int j = i - which * n4each;
  const float4* in = (which == 0) ? a : (which == 1) ? b : (which == 2) ? c : d;
  ushort4* out = (which == 0) ? oa : (which == 1) ? ob : (which == 2) ? oc : od;
  if (which > 3) return;
  float4 f = in[j];
  ushort4 o;
  o.x = (ushort)f2bf(f.x);
  o.y = (ushort)f2bf(f.y);
  o.z = (ushort)f2bf(f.z);
  o.w = (ushort)f2bf(f.w);
  out[j] = o;
}

// ---------------- embedding-bag sum + LayerNorm + ReLU (bf16 in/out) ----------------
__global__ __launch_bounds__(256) void k_embed_ln(
    const int* __restrict__ x, const ushort* __restrict__ emb,
    const float* __restrict__ g, const float* __restrict__ b,
    ushort* __restrict__ h, int n0) {
  unsigned gid = blockIdx.x * blockDim.x + threadIdx.x;
  int node = gid >> 6;
  int lane = threadIdx.x & 63;
  if (node >= n0) return;
  const int* xr = x + (size_t)node * 16;
  float sx = 0.f, sy = 0.f;
#pragma unroll
  for (int w = 0; w < 16; ++w) {
    int t = xr[w];
    uint u = ((const uint*)(emb + (size_t)t * C))[lane];
    sx += bf_lo(u);
    sy += bf_hi(u);
  }
  float red = sx + sy;
#pragma unroll
  for (int off = 32; off; off >>= 1) red += __shfl_xor(red, off, 64);
  float mu = red * (1.f / C);
  float cx = sx - mu, cy = sy - mu;
  float sq = cx * cx + cy * cy;
#pragma unroll
  for (int off = 32; off; off >>= 1) sq += __shfl_xor(sq, off, 64);
  float rs = rsqrtf(sq * (1.f / C) + 1e-5f);
  float2 gg = ((const float2*)g)[lane];
  float2 bb = ((const float2*)b)[lane];
  float ox = fmaxf(cx * rs * gg.x + bb.x, 0.f);
  float oy = fmaxf(cy * rs * gg.y + bb.y, 0.f);
  ((uint*)(h + (size_t)node * C))[lane] = pack2(ox, oy);
}

// ---------------- CSR build ----------------
__global__ __launch_bounds__(256) void k_hist2(
    const int* __restrict__ dst1, int* __restrict__ deg1, int e1,
    const int* __restrict__ dst2, int* __restrict__ deg2, int e2) {
  int i = blockIdx.x * blockDim.x + threadIdx.x;
  if (i < e1) atomicAdd(&deg1[dst1[i]], 1);
  else if (i < e1 + e2) atomicAdd(&deg2[dst2[i - e1]], 1);
}

__global__ __launch_bounds__(1024) void k_scan2(
    const int* __restrict__ degA, int* __restrict__ rpA, int nA,
    const int* __restrict__ degB, int* __restrict__ rpB, int nB) {
  const int* deg = blockIdx.x ? degB : degA;
  int* rowptr = blockIdx.x ? rpB : rpA;
  int n = blockIdx.x ? nB : nA;
  __shared__ int part[1024];
  int t = threadIdx.x;
  int chunk = (n + 1023) >> 10;
  int lo = t * chunk;
  int hi = min(lo + chunk, n);
  int s = 0;
  for (int i = lo; i < hi; ++i) s += deg[i];
  part[t] = s;
  __syncthreads();
  for (int off = 1; off < 1024; off <<= 1) {
    int v = (t >= off) ? part[t - off] : 0;
    __syncthreads();
    part[t] += v;
    __syncthreads();
  }
  int run = (t == 0) ? 0 : part[t - 1];
  for (int i = lo; i < hi; ++i) {
    rowptr[i] = run;
    run += deg[i];
  }
  if (t == 1023) rowptr[n] = part[1023];
}

__global__ __launch_bounds__(256) void k_bucket2(
    const int* __restrict__ src1, const int* __restrict__ dst1,
    const int* __restrict__ rp1, int* __restrict__ cur1,
    int* __restrict__ eidx1, int e1,
    const int* __restrict__ src2, const int* __restrict__ dst2,
    const int* __restrict__ rp2, int* __restrict__ cur2,
    int* __restrict__ eidx2, int e2) {
  int i = blockIdx.x * blockDim.x + threadIdx.x;
  if (i < e1) {
    int d = dst1[i];
    eidx1[rp1[d] + atomicAdd(&cur1[d], 1)] = src1[i];
  } else if (i < e1 + e2) {
    int j = i - e1;
    int d = dst2[j];
    eidx2[rp2[d] + atomicAdd(&cur2[d], 1)] = src2[j];
  }
}

// ---------------- Aggregate: one wave per dst node, mean of bf16 h[src] -> bf16 ----------------
__global__ __launch_bounds__(256) void k_aggregate(
    const int* __restrict__ rowptr, const int* __restrict__ eidx,
    const ushort* __restrict__ h, ushort* __restrict__ mean, int ntgt) {
  unsigned gid = blockIdx.x * blockDim.x + threadIdx.x;
  int node = gid >> 6;
  int lane = threadIdx.x & 63;
  if (node >= ntgt) return;
  int row = rowptr[node];
  int end = rowptr[node + 1];
  int dg = end - row;
  float sx = 0.f, sy = 0.f;
  for (int j0 = row; j0 < end; j0 += 64) {
    int idx = j0 + lane;
    int e = (idx < end) ? eidx[idx] : 0;
    int cnt = min(64, end - j0);
    int d = 0;
    for (; d + 3 < cnt; d += 4) {
      int s0 = __shfl(e, d, 64);
      int s1 = __shfl(e, d + 1, 64);
      int s2 = __shfl(e, d + 2, 64);
      int s3 = __shfl(e, d + 3, 64);
      uint u0 = ((const uint*)(h + (size_t)s0 * C))[lane];
      uint u1 = ((const uint*)(h + (size_t)s1 * C))[lane];
      uint u2 = ((const uint*)(h + (size_t)s2 * C))[lane];
      uint u3 = ((const uint*)(h + (size_t)s3 * C))[lane];
      sx += bf_lo(u0) + bf_lo(u1) + bf_lo(u2) + bf_lo(u3);
      sy += bf_hi(u0) + bf_hi(u1) + bf_hi(u2) + bf_hi(u3);
    }
    for (; d < cnt; ++d) {
      int s0 = __shfl(e, d, 64);
      uint u0 = ((const uint*)(h + (size_t)s0 * C))[lane];
      sx += bf_lo(u0);
      sy += bf_hi(u0);
    }
  }
  float sc = 1.f / (float)max(dg, 1);
  ((uint*)(mean + (size_t)node * C))[lane] = pack2(sx * sc, sy * sc);
}

// ---------------- Combine via MFMA: out = mean @ Wl^T + bl + h @ Wr^T (+ReLU) ----------------
// one wave per 16x16 output tile pair; block = 4 waves covers one m-tile x all 8 n-tiles.
// A-frag: lane holds X[mbase+(lane&15)][kc*32 + (lane>>4)*8 + j], j=0..7 (16B row load)
// B-frag: lane holds W[nbase+(lane&15)][kc*32 + (lane>>4)*8 + j]     (16B row load)
// C/D:    lane,reg -> out[mbase + (lane>>4)*4 + reg][nbase + (lane&15)]   [m89-verified]
template <bool RELU, bool BF16OUT>
__global__ __launch_bounds__(256) void k_combine_mfma(
    const ushort* __restrict__ meanb, const ushort* __restrict__ hb,
    const ushort* __restrict__ Wlb, const float* __restrict__ bl,
    const ushort* __restrict__ Wrb, void* __restrict__ outp, int ntgt) {
  int wave = threadIdx.x >> 6;
  int lane = threadIdx.x & 63;
  int mbase = blockIdx.x * 16;
  int r16 = lane & 15;
  int quad = lane >> 4;
  int arow = min(mbase + r16, ntgt - 1);
  const ushort* mrow = meanb + (size_t)arow * C;
  const ushort* hrow = hb + (size_t)arow * C;
  int koff = quad * 8;
  bf16x8 am[4], ah[4];
#pragma unroll
  for (int kc = 0; kc < 4; ++kc) {
    am[kc] = *(const bf16x8*)(mrow + kc * 32 + koff);
    ah[kc] = *(const bf16x8*)(hrow + kc * 32 + koff);
  }
#pragma unroll
  for (int t = 0; t < 2; ++t) {
    int nbase = (wave * 2 + t) * 16;
    float b = bl[nbase + r16];
    f32x4 acc = {b, b, b, b};
    const ushort* wlrow = Wlb + (size_t)(nbase + r16) * C;
    const ushort* wrrow = Wrb + (size_t)(nbase + r16) * C;
#pragma unroll
    for (int kc = 0; kc < 4; ++kc) {
      bf16x8 wl = *(const bf16x8*)(wlrow + kc * 32 + koff);
      acc = __builtin_amdgcn_mfma_f32_16x16x32_bf16(am[kc], wl, acc, 0, 0, 0);
      bf16x8 wr = *(const bf16x8*)(wrrow + kc * 32 + koff);
      acc = __builtin_amdgcn_mfma_f32_16x16x32_bf16(ah[kc], wr, acc, 0, 0, 0);
    }
#pragma unroll
    for (int r = 0; r < 4; ++r) {
      int row = mbase + quad * 4 + r;
      if (row < ntgt) {
        float v = acc[r];
        if (RELU) v = fmaxf(v, 0.f);
        if (BF16OUT)
          ((ushort*)outp)[(size_t)row * C + nbase + r16] = (ushort)f2bf(v);
        else
          ((float*)outp)[(size_t)row * C + nbase + r16] = v;
      }
    }
  }
}

extern "C" void kernel_launch(void* const* d_in, const int* in_sizes, int n_in,
                              void* d_out, int out_size, void* d_ws, size_t ws_size,
                              hipStream_t stream) {
  const int*   x    = (const int*)d_in[0];
  const int*   src1 = (const int*)d_in[1];
  const int*   dst1 = (const int*)d_in[2];
  const int*   src2 = (const int*)d_in[3];
  const int*   dst2 = (const int*)d_in[4];
  const float* emb  = (const float*)d_in[7];
  const float* ln_g = (const float*)d_in[8];
  const float* ln_b = (const float*)d_in[9];
  const float* Wl1  = (const float*)d_in[10];
  const float* bl1  = (const float*)d_in[11];
  const float* Wr1  = (const float*)d_in[12];
  const float* Wl2  = (const float*)d_in[13];
  const float* bl2  = (const float*)d_in[14];
  const float* Wr2  = (const float*)d_in[15];

  const int N0 = in_sizes[0] / 16;   // 100000
  const int E1 = in_sizes[1];        // 500000
  const int E2 = in_sizes[3];        // 100000
  const int N1 = 25000;
  const int N2 = 5000;
  const int LEAF_ELEMS = in_sizes[7];  // 50000*128
  const int W_ELEMS = C * C;           // 16384 per weight matrix

  char* ws = (char*)d_ws;
  size_t off = 0;
  auto alloc = [&](size_t bytes) {
    char* p = ws + off;
    off += (bytes + 255) & ~(size_t)255;
    return p;
  };
  ushort* embh  = (ushort*)alloc((size_t)LEAF_ELEMS * 2);  // 12.8 MB
  ushort* h0    = (ushort*)alloc((size_t)N0 * C * 2);      // 25.6 MB
  ushort* h1    = (ushort*)alloc((size_t)N1 * C * 2);      //  6.4 MB
  ushort* mean1 = (ushort*)alloc((size_t)N1 * C * 2);      //  6.4 MB
  ushort* mean2 = (ushort*)alloc((size_t)N2 * C * 2);      //  1.28 MB
  ushort* Wl1b  = (ushort*)alloc((size_t)W_ELEMS * 2);
  ushort* Wr1b  = (ushort*)alloc((size_t)W_ELEMS * 2);
  ushort* Wl2b  = (ushort*)alloc((size_t)W_ELEMS * 2);
  ushort* Wr2b  = (ushort*)alloc((size_t)W_ELEMS * 2);
  int*    eidx1 = (int*)alloc((size_t)E1 * 4);
  int*    eidx2 = (int*)alloc((size_t)E2 * 4);
  char*   zbase = ws + off;
  int*    deg1 = (int*)alloc((size_t)N1 * 4);
  int*    cur1 = (int*)alloc((size_t)N1 * 4);
  int*    deg2 = (int*)alloc((size_t)N2 * 4);
  int*    cur2 = (int*)alloc((size_t)N2 * 4);
  size_t  zbytes = (size_t)((ws + off) - zbase);
  int*    rp1 = (int*)alloc((size_t)(N1 + 1) * 4);
  int*    rp2 = (int*)alloc((size_t)(N2 + 1) * 4);

  float* out = (float*)d_out;

  hipMemsetAsync(zbase, 0, zbytes, stream);

  // 0) convert table + weights to bf16
  k_cvt<<<(LEAF_ELEMS / 4 + 255) / 256, 256, 0, stream>>>(
      (const float4*)emb, (ushort4*)embh, LEAF_ELEMS / 4);
  {
    int n4each = W_ELEMS / 4;
    k_cvt4<<<(4 * n4each + 255) / 256, 256, 0, stream>>>(
        (const float4*)Wl1, (const float4*)Wr1, (const float4*)Wl2, (const float4*)Wr2,
        (ushort4*)Wl1b, (ushort4*)Wr1b, (ushort4*)Wl2b, (ushort4*)Wr2b, n4each);
  }

  // 1) embedding-bag + LN + ReLU -> h0 bf16
  k_embed_ln<<<(N0 + 3) / 4, 256, 0, stream>>>(x, embh, ln_g, ln_b, h0, N0);

  // 2) CSR build (both graphs)
  k_hist2<<<(E1 + E2 + 255) / 256, 256, 0, stream>>>(dst1, deg1, E1, dst2, deg2, E2);
  k_scan2<<<2, 1024, 0, stream>>>(deg1, rp1, N1, deg2, rp2, N2);
  k_bucket2<<<(E1 + E2 + 255) / 256, 256, 0, stream>>>(
      src1, dst1, rp1, cur1, eidx1, E1, src2, dst2, rp2, cur2, eidx2, E2);

  // 3) conv1
  k_aggregate<<<(N1 + 3) / 4, 256, 0, stream>>>(rp1, eidx1, h0, mean1, N1);
  k_combine_mfma<true, true><<<(N1 + 15) / 16, 256, 0, stream>>>(
      mean1, h0, Wl1b, bl1, Wr1b, h1, N1);

  // 4) conv2
  k_aggregate<<<(N2 + 3) / 4, 256, 0, stream>>>(rp2, eidx2, h1, mean2, N2);
  k_combine_mfma<false, false><<<(N2 + 15) / 16, 256, 0, stream>>>(
      mean2, h1, Wl2b, bl2, Wr2b, out, N2);
}

// Round 5
// 269.451 us; speedup vs baseline: 4.9209x; 1.1278x over previous
//
#include <hip/hip_runtime.h>

#define C 128
#define LDSPAD 136  // padded LDS row stride (ushorts): 68 words -> 2-way (free) bank aliasing

typedef unsigned int uint;
typedef unsigned short ushort;
typedef __attribute__((ext_vector_type(8))) short bf16x8;
typedef __attribute__((ext_vector_type(4))) float f32x4;

__device__ __forceinline__ float bf_lo(uint u) { return __uint_as_float(u << 16); }
__device__ __forceinline__ float bf_hi(uint u) { return __uint_as_float(u & 0xffff0000u); }
__device__ __forceinline__ uint f2bf(float f) {
  uint u = __float_as_uint(f);
  return (u + 0x7fffu + ((u >> 16) & 1u)) >> 16;  // RNE, no NaN inputs
}
__device__ __forceinline__ uint pack2(float a, float b) { return f2bf(a) | (f2bf(b) << 16); }

// ---------------- Kernel 1: prep — emb->bf16, 4 weights->bf16, zero deg/cur ----------------
// wb layout: [Wl1 | Wr1 | Wl2 | Wr2], 16384 ushorts each
__global__ __launch_bounds__(256) void k_prep(
    const float4* __restrict__ emb, ushort4* __restrict__ embh, int n4,
    const float4* __restrict__ w0, const float4* __restrict__ w1,
    const float4* __restrict__ w2, const float4* __restrict__ w3,
    ushort4* __restrict__ wb, int nw4each,
    int4* __restrict__ zb, int nz4) {
  int i = blockIdx.x * blockDim.x + threadIdx.x;
  if (i < n4) {
    float4 f = emb[i];
    ushort4 o = {(ushort)f2bf(f.x), (ushort)f2bf(f.y), (ushort)f2bf(f.z), (ushort)f2bf(f.w)};
    embh[i] = o;
  }
  if (i < 4 * nw4each) {
    int m = i / nw4each;
    int j = i - m * nw4each;
    const float4* w = (m == 0) ? w0 : (m == 1) ? w1 : (m == 2) ? w2 : w3;
    float4 f = w[j];
    ushort4 o = {(ushort)f2bf(f.x), (ushort)f2bf(f.y), (ushort)f2bf(f.z), (ushort)f2bf(f.w)};
    wb[i] = o;
  }
  if (i < nz4) {
    int4 z = {0, 0, 0, 0};
    zb[i] = z;
  }
}

// ---------------- Kernel 2: embedding-bag + LN + ReLU, fused edge histogram ----------------
// one wave per node; lane (grp=lane>>5, sub=lane&31) owns channels 4*sub..4*sub+3,
// group g loads token w+g -> each load fetches 2 embedding rows (uint2/lane).
__global__ __launch_bounds__(256) void k_embed_hist(
    const int* __restrict__ x, const ushort* __restrict__ emb,
    const float* __restrict__ g, const float* __restrict__ b,
    ushort* __restrict__ h, int n0,
    const int* __restrict__ dst1, int* __restrict__ deg1, int e1,
    const int* __restrict__ dst2, int* __restrict__ deg2, int e2,
    int epb) {
  // fused histogram slice
  {
    long base = (long)blockIdx.x * epb + threadIdx.x;
    if (threadIdx.x < epb) {
      if (base < e1) atomicAdd(&deg1[dst1[base]], 1);
      else if (base < (long)e1 + e2) atomicAdd(&deg2[dst2[base - e1]], 1);
    }
  }
  int node = blockIdx.x * 4 + (threadIdx.x >> 6);
  if (node >= n0) return;
  int lane = threadIdx.x & 63;
  int grp = lane >> 5, sub = lane & 31;
  const int* xr = x + (size_t)node * 16;
  float s0 = 0.f, s1 = 0.f, s2 = 0.f, s3 = 0.f;
#pragma unroll
  for (int w = 0; w < 16; w += 2) {
    int tok = xr[w + grp];
    uint2 u = ((const uint2*)(emb + (size_t)tok * C))[sub];
    s0 += bf_lo(u.x); s1 += bf_hi(u.x); s2 += bf_lo(u.y); s3 += bf_hi(u.y);
  }
  // combine the two token-halves: lanes l and l^32 own the same channels
  s0 += __shfl_xor(s0, 32, 64);
  s1 += __shfl_xor(s1, 32, 64);
  s2 += __shfl_xor(s2, 32, 64);
  s3 += __shfl_xor(s3, 32, 64);
  // mean over 128 channels (values duplicated across halves; reduce within 32)
  float red = s0 + s1 + s2 + s3;
#pragma unroll
  for (int off = 16; off; off >>= 1) red += __shfl_xor(red, off, 64);
  float mu = red * (1.f / C);
  float c0 = s0 - mu, c1 = s1 - mu, c2 = s2 - mu, c3 = s3 - mu;
  float sq = c0 * c0 + c1 * c1 + c2 * c2 + c3 * c3;
#pragma unroll
  for (int off = 16; off; off >>= 1) sq += __shfl_xor(sq, off, 64);
  float rs = rsqrtf(sq * (1.f / C) + 1e-5f);
  float4 gg = ((const float4*)g)[sub];
  float4 bb = ((const float4*)b)[sub];
  float o0 = fmaxf(c0 * rs * gg.x + bb.x, 0.f);
  float o1 = fmaxf(c1 * rs * gg.y + bb.y, 0.f);
  float o2 = fmaxf(c2 * rs * gg.z + bb.z, 0.f);
  float o3 = fmaxf(c3 * rs * gg.w + bb.w, 0.f);
  if (grp == 0) {
    ushort4 o = {(ushort)f2bf(o0), (ushort)f2bf(o1), (ushort)f2bf(o2), (ushort)f2bf(o3)};
    ((ushort4*)(h + (size_t)node * C))[sub] = o;
  }
}

// ---------------- Kernel 3: exclusive scan (block 0 -> graph1, block 1 -> graph2) ----------------
__global__ __launch_bounds__(1024) void k_scan2(
    const int* __restrict__ degA, int* __restrict__ rpA, int nA,
    const int* __restrict__ degB, int* __restrict__ rpB, int nB) {
  const int* deg = blockIdx.x ? degB : degA;
  int* rowptr = blockIdx.x ? rpB : rpA;
  int n = blockIdx.x ? nB : nA;
  __shared__ int part[1024];
  int t = threadIdx.x;
  int chunk = (n + 1023) >> 10;
  int lo = t * chunk;
  int hi = min(lo + chunk, n);
  int s = 0;
  for (int i = lo; i < hi; ++i) s += deg[i];
  part[t] = s;
  __syncthreads();
  for (int off = 1; off < 1024; off <<= 1) {
    int v = (t >= off) ? part[t - off] : 0;
    __syncthreads();
    part[t] += v;
    __syncthreads();
  }
  int run = (t == 0) ? 0 : part[t - 1];
  for (int i = lo; i < hi; ++i) {
    rowptr[i] = run;
    run += deg[i];
  }
  if (t == 1023) rowptr[n] = part[1023];
}

// ---------------- Kernel 4: bucket src ids (both graphs) ----------------
__global__ __launch_bounds__(256) void k_bucket2(
    const int* __restrict__ src1, const int* __restrict__ dst1,
    const int* __restrict__ rp1, int* __restrict__ cur1,
    int* __restrict__ eidx1, int e1,
    const int* __restrict__ src2, const int* __restrict__ dst2,
    const int* __restrict__ rp2, int* __restrict__ cur2,
    int* __restrict__ eidx2, int e2) {
  int i = blockIdx.x * blockDim.x + threadIdx.x;
  if (i < e1) {
    int d = dst1[i];
    eidx1[rp1[d] + atomicAdd(&cur1[d], 1)] = src1[i];
  } else if (i < e1 + e2) {
    int j = i - e1;
    int d = dst2[j];
    eidx2[rp2[d] + atomicAdd(&cur2[d], 1)] = src2[j];
  }
}

// ---------------- Kernel 5/6: fused conv = aggregate(mean) + MFMA combine ----------------
// block = 512 (8 waves) handles 16 target nodes.
// Phase A: wave w aggregates nodes mbase+2w, mbase+2w+1 (2 edge rows per load via uint2),
//          writes bf16 mean rows into padded LDS tile.
// Phase B: wave w computes output n-tile w (16 cols): 8 MFMAs (mean@Wl + h@Wr), bias in acc.
// C/D layout: lane,reg -> out[mbase + (lane>>4)*4 + reg][nbase + (lane&15)]  [m89-verified]
template <bool RELU, bool BF16OUT>
__global__ __launch_bounds__(512) void k_conv(
    const int* __restrict__ rowptr, const int* __restrict__ eidx,
    const ushort* __restrict__ h, const ushort* __restrict__ Wlb,
    const float* __restrict__ bl, const ushort* __restrict__ Wrb,
    void* __restrict__ outp, int ntgt) {
  __shared__ ushort smean[16 * LDSPAD];
  int wave = threadIdx.x >> 6;
  int lane = threadIdx.x & 63;
  int grp = lane >> 5, sub = lane & 31;
  int mbase = blockIdx.x * 16;

  // ---- Phase A: aggregate ----
#pragma unroll
  for (int rep = 0; rep < 2; ++rep) {
    int nl = wave * 2 + rep;        // local row 0..15
    int node = mbase + nl;
    float s0 = 0.f, s1 = 0.f, s2 = 0.f, s3 = 0.f;
    int dg = 0;
    if (node < ntgt) {
      int row = rowptr[node], end = rowptr[node + 1];
      dg = end - row;
      for (int j = row; j < end; j += 64) {
        int idx = j + lane;
        int e = (idx < end) ? eidx[idx] : 0;
        int cnt = min(64, end - j);
        int d = 0;
        for (; d + 8 <= cnt; d += 8) {  // 4 loads in flight, 8 edge rows
          int a0 = __shfl(e, d + grp, 64);
          int a1 = __shfl(e, d + 2 + grp, 64);
          int a2 = __shfl(e, d + 4 + grp, 64);
          int a3 = __shfl(e, d + 6 + grp, 64);
          uint2 u0 = ((const uint2*)(h + (size_t)a0 * C))[sub];
          uint2 u1 = ((const uint2*)(h + (size_t)a1 * C))[sub];
          uint2 u2 = ((const uint2*)(h + (size_t)a2 * C))[sub];
          uint2 u3 = ((const uint2*)(h + (size_t)a3 * C))[sub];
          s0 += bf_lo(u0.x) + bf_lo(u1.x) + bf_lo(u2.x) + bf_lo(u3.x);
          s1 += bf_hi(u0.x) + bf_hi(u1.x) + bf_hi(u2.x) + bf_hi(u3.x);
          s2 += bf_lo(u0.y) + bf_lo(u1.y) + bf_lo(u2.y) + bf_lo(u3.y);
          s3 += bf_hi(u0.y) + bf_hi(u1.y) + bf_hi(u2.y) + bf_hi(u3.y);
        }
        for (; d + 2 <= cnt; d += 2) {
          int a0 = __shfl(e, d + grp, 64);
          uint2 u = ((const uint2*)(h + (size_t)a0 * C))[sub];
          s0 += bf_lo(u.x); s1 += bf_hi(u.x); s2 += bf_lo(u.y); s3 += bf_hi(u.y);
        }
        if (d < cnt) {  // odd tail: single edge, group 0 only
          int a0 = __shfl(e, d, 64);
          if (grp == 0) {
            uint2 u = ((const uint2*)(h + (size_t)a0 * C))[sub];
            s0 += bf_lo(u.x); s1 += bf_hi(u.x); s2 += bf_lo(u.y); s3 += bf_hi(u.y);
          }
        }
      }
    }
    s0 += __shfl_xor(s0, 32, 64);
    s1 += __shfl_xor(s1, 32, 64);
    s2 += __shfl_xor(s2, 32, 64);
    s3 += __shfl_xor(s3, 32, 64);
    float sc = 1.f / (float)max(dg, 1);
    if (grp == 0) {
      ushort4 o = {(ushort)f2bf(s0 * sc), (ushort)f2bf(s1 * sc),
                   (ushort)f2bf(s2 * sc), (ushort)f2bf(s3 * sc)};
      *(ushort4*)(smean + nl * LDSPAD + sub * 4) = o;
    }
  }
  __syncthreads();

  // ---- Phase B: MFMA combine ----
  int r16 = lane & 15;
  int quad = lane >> 4;
  int koff = quad * 8;
  bf16x8 am[4], ah[4];
  int hr = min(mbase + r16, ntgt - 1);
  const ushort* hrow = h + (size_t)hr * C;
#pragma unroll
  for (int kc = 0; kc < 4; ++kc) {
    am[kc] = *(const bf16x8*)(smean + r16 * LDSPAD + kc * 32 + koff);
    ah[kc] = *(const bf16x8*)(hrow + kc * 32 + koff);
  }
  int nbase = wave * 16;
  float bias = bl[nbase + r16];
  f32x4 acc = {bias, bias, bias, bias};
  const ushort* wlrow = Wlb + (size_t)(nbase + r16) * C;
  const ushort* wrrow = Wrb + (size_t)(nbase + r16) * C;
#pragma unroll
  for (int kc = 0; kc < 4; ++kc) {
    bf16x8 wl = *(const bf16x8*)(wlrow + kc * 32 + koff);
    acc = __builtin_amdgcn_mfma_f32_16x16x32_bf16(am[kc], wl, acc, 0, 0, 0);
    bf16x8 wr = *(const bf16x8*)(wrrow + kc * 32 + koff);
    acc = __builtin_amdgcn_mfma_f32_16x16x32_bf16(ah[kc], wr, acc, 0, 0, 0);
  }
#pragma unroll
  for (int r = 0; r < 4; ++r) {
    int row = mbase + quad * 4 + r;
    if (row < ntgt) {
      float v = acc[r];
      if (RELU) v = fmaxf(v, 0.f);
      if (BF16OUT)
        ((ushort*)outp)[(size_t)row * C + nbase + r16] = (ushort)f2bf(v);
      else
        ((float*)outp)[(size_t)row * C + nbase + r16] = v;
    }
  }
}

extern "C" void kernel_launch(void* const* d_in, const int* in_sizes, int n_in,
                              void* d_out, int out_size, void* d_ws, size_t ws_size,
                              hipStream_t stream) {
  const int*   x    = (const int*)d_in[0];
  const int*   src1 = (const int*)d_in[1];
  const int*   dst1 = (const int*)d_in[2];
  const int*   src2 = (const int*)d_in[3];
  const int*   dst2 = (const int*)d_in[4];
  const float* emb  = (const float*)d_in[7];
  const float* ln_g = (const float*)d_in[8];
  const float* ln_b = (const float*)d_in[9];
  const float* Wl1  = (const float*)d_in[10];
  const float* bl1  = (const float*)d_in[11];
  const float* Wr1  = (const float*)d_in[12];
  const float* Wl2  = (const float*)d_in[13];
  const float* bl2  = (const float*)d_in[14];
  const float* Wr2  = (const float*)d_in[15];

  const int N0 = in_sizes[0] / 16;   // 100000
  const int E1 = in_sizes[1];        // 500000
  const int E2 = in_sizes[3];        // 100000
  const int N1 = 25000;
  const int N2 = 5000;
  const int LEAF_ELEMS = in_sizes[7];  // 50000*128
  const int W_ELEMS = C * C;

  char* ws = (char*)d_ws;
  size_t off = 0;
  auto alloc = [&](size_t bytes) {
    char* p = ws + off;
    off += (bytes + 255) & ~(size_t)255;
    return p;
  };
  ushort* embh = (ushort*)alloc((size_t)LEAF_ELEMS * 2);   // 12.8 MB
  ushort* h0   = (ushort*)alloc((size_t)N0 * C * 2);       // 25.6 MB
  ushort* h1   = (ushort*)alloc((size_t)N1 * C * 2);       //  6.4 MB
  ushort* wb   = (ushort*)alloc((size_t)4 * W_ELEMS * 2);  // Wl1|Wr1|Wl2|Wr2
  int*    eidx1 = (int*)alloc((size_t)E1 * 4);
  int*    eidx2 = (int*)alloc((size_t)E2 * 4);
  // zeroed-by-k_prep region (contiguous, 16B-aligned size)
  char*   zbase = ws + off;
  int*    deg1 = (int*)alloc((size_t)N1 * 4);
  int*    cur1 = (int*)alloc((size_t)N1 * 4);
  int*    deg2 = (int*)alloc((size_t)N2 * 4);
  int*    cur2 = (int*)alloc((size_t)N2 * 4);
  size_t  zbytes = (size_t)((ws + off) - zbase);
  int*    rp1 = (int*)alloc((size_t)(N1 + 1) * 4);
  int*    rp2 = (int*)alloc((size_t)(N2 + 1) * 4);

  float* out = (float*)d_out;
  ushort* Wl1b = wb;
  ushort* Wr1b = wb + W_ELEMS;
  ushort* Wl2b = wb + 2 * W_ELEMS;
  ushort* Wr2b = wb + 3 * W_ELEMS;

  // 1) prep: converts + zeroing (no memset dispatch)
  {
    int n4 = LEAF_ELEMS / 4;
    int nw4each = W_ELEMS / 4;
    int nz4 = (int)(zbytes / 16);
    k_prep<<<(n4 + 255) / 256, 256, 0, stream>>>(
        (const float4*)emb, (ushort4*)embh, n4,
        (const float4*)Wl1, (const float4*)Wr1, (const float4*)Wl2, (const float4*)Wr2,
        (ushort4*)wb, nw4each, (int4*)zbase, nz4);
  }

  // 2) embed + LN + ReLU + fused histogram
  {
    int nblocks = (N0 + 3) / 4;  // 25000
    int epb = (E1 + E2 + nblocks - 1) / nblocks;  // 24
    k_embed_hist<<<nblocks, 256, 0, stream>>>(
        x, embh, ln_g, ln_b, h0, N0, dst1, deg1, E1, dst2, deg2, E2, epb);
  }

  // 3) scan, 4) bucket
  k_scan2<<<2, 1024, 0, stream>>>(deg1, rp1, N1, deg2, rp2, N2);
  k_bucket2<<<(E1 + E2 + 255) / 256, 256, 0, stream>>>(
      src1, dst1, rp1, cur1, eidx1, E1, src2, dst2, rp2, cur2, eidx2, E2);

  // 5) conv1 (fused aggregate + MFMA combine + ReLU) -> h1 bf16
  k_conv<true, true><<<(N1 + 15) / 16, 512, 0, stream>>>(
      rp1, eidx1, h0, Wl1b, bl1, Wr1b, h1, N1);

  // 6) conv2 -> d_out fp32
  k_conv<false, false><<<(N2 + 15) / 16, 512, 0, stream>>>(
      rp2, eidx2, h1, Wl2b, bl2, Wr2b, out, N2);
}

// Round 6
// 233.149 us; speedup vs baseline: 5.6871x; 1.1557x over previous
//
#include <hip/hip_runtime.h>

#define C 128
#define LDSPAD 136  // padded LDS row stride (ushorts); 2-way bank aliasing is free
#define CAP 64      // padded-CSR slots per node (mean deg 20, Poisson tail < 1e-13)

typedef unsigned int uint;
typedef unsigned short ushort;
typedef __attribute__((ext_vector_type(8))) short bf16x8;
typedef __attribute__((ext_vector_type(4))) float f32x4;

__device__ __forceinline__ float bf_lo(uint u) { return __uint_as_float(u << 16); }
__device__ __forceinline__ float bf_hi(uint u) { return __uint_as_float(u & 0xffff0000u); }
__device__ __forceinline__ uint f2bf(float f) {
  uint u = __float_as_uint(f);
  return (u + 0x7fffu + ((u >> 16) & 1u)) >> 16;  // RNE, no NaN inputs
}

// ---------------- Kernel 1: prep — emb->bf16, 4 weights->bf16, zero cnt arrays ----------------
__global__ __launch_bounds__(256) void k_prep(
    const float4* __restrict__ emb, ushort4* __restrict__ embh, int n4,
    const float4* __restrict__ w0, const float4* __restrict__ w1,
    const float4* __restrict__ w2, const float4* __restrict__ w3,
    ushort4* __restrict__ wb, int nw4each,
    int4* __restrict__ zb, int nz4) {
  int i = blockIdx.x * blockDim.x + threadIdx.x;
  if (i < n4) {
    float4 f = emb[i];
    ushort4 o = {(ushort)f2bf(f.x), (ushort)f2bf(f.y), (ushort)f2bf(f.z), (ushort)f2bf(f.w)};
    embh[i] = o;
  }
  if (i < 4 * nw4each) {
    int m = i / nw4each;
    int j = i - m * nw4each;
    const float4* w = (m == 0) ? w0 : (m == 1) ? w1 : (m == 2) ? w2 : w3;
    float4 f = w[j];
    ushort4 o = {(ushort)f2bf(f.x), (ushort)f2bf(f.y), (ushort)f2bf(f.z), (ushort)f2bf(f.w)};
    wb[i] = o;
  }
  if (i < nz4) {
    int4 z = {0, 0, 0, 0};
    zb[i] = z;
  }
}

// ---------------- Kernel 2: padded-CSR bucket (both graphs) ----------------
__global__ __launch_bounds__(256) void k_bucket2(
    const int* __restrict__ src1, const int* __restrict__ dst1,
    int* __restrict__ cnt1, int* __restrict__ slots1, int e1,
    const int* __restrict__ src2, const int* __restrict__ dst2,
    int* __restrict__ cnt2, int* __restrict__ slots2, int e2) {
  int i = blockIdx.x * blockDim.x + threadIdx.x;
  if (i < e1) {
    int d = dst1[i];
    int p = atomicAdd(&cnt1[d], 1);
    if (p < CAP) slots1[d * CAP + p] = src1[i];
  } else if (i < e1 + e2) {
    int j = i - e1;
    int d = dst2[j];
    int p = atomicAdd(&cnt2[d], 1);
    if (p < CAP) slots2[d * CAP + p] = src2[j];
  }
}

// ---------------- Kernel 3: embedding-bag sum + LayerNorm + ReLU ----------------
// one wave per node; half grp loads token w+grp (2 rows per load instr, uint2/lane);
// 16 tokens fetched once by lanes 0..15 and broadcast by shfl.
__global__ __launch_bounds__(256) void k_embed(
    const int* __restrict__ x, const ushort* __restrict__ emb,
    const float* __restrict__ g, const float* __restrict__ b,
    ushort* __restrict__ h, int n0) {
  int node = blockIdx.x * 4 + (threadIdx.x >> 6);
  int lane = threadIdx.x & 63;
  if (node >= n0) return;
  int grp = lane >> 5, sub = lane & 31;
  int xv = x[(size_t)node * 16 + (lane & 15)];
  float s0 = 0.f, s1 = 0.f, s2 = 0.f, s3 = 0.f;
#pragma unroll
  for (int w = 0; w < 16; w += 2) {
    int tok = __shfl(xv, w + grp, 64);
    uint2 u = ((const uint2*)(emb + (size_t)tok * C))[sub];
    s0 += bf_lo(u.x); s1 += bf_hi(u.x); s2 += bf_lo(u.y); s3 += bf_hi(u.y);
  }
  // combine the two token-halves (lanes l and l^32 own the same channels)
  s0 += __shfl_xor(s0, 32, 64);
  s1 += __shfl_xor(s1, 32, 64);
  s2 += __shfl_xor(s2, 32, 64);
  s3 += __shfl_xor(s3, 32, 64);
  float red = s0 + s1 + s2 + s3;
#pragma unroll
  for (int off = 16; off; off >>= 1) red += __shfl_xor(red, off, 64);
  float mu = red * (1.f / C);
  float c0 = s0 - mu, c1 = s1 - mu, c2 = s2 - mu, c3 = s3 - mu;
  float sq = c0 * c0 + c1 * c1 + c2 * c2 + c3 * c3;
#pragma unroll
  for (int off = 16; off; off >>= 1) sq += __shfl_xor(sq, off, 64);
  float rs = rsqrtf(sq * (1.f / C) + 1e-5f);
  float4 gg = ((const float4*)g)[sub];
  float4 bb = ((const float4*)b)[sub];
  float o0 = fmaxf(c0 * rs * gg.x + bb.x, 0.f);
  float o1 = fmaxf(c1 * rs * gg.y + bb.y, 0.f);
  float o2 = fmaxf(c2 * rs * gg.z + bb.z, 0.f);
  float o3 = fmaxf(c3 * rs * gg.w + bb.w, 0.f);
  if (grp == 0) {
    ushort4 o = {(ushort)f2bf(o0), (ushort)f2bf(o1), (ushort)f2bf(o2), (ushort)f2bf(o3)};
    ((ushort4*)(h + (size_t)node * C))[sub] = o;
  }
}

// ---------------- Kernel 4/5: fused conv = aggregate(mean) + MFMA combine ----------------
// block = 512 (8 waves) -> 16 target nodes.
// Phase A: each HALF-wave aggregates one node (2 nodes/wave in parallel); edge ids in
//          registers (<=64 via CAP), beyond-cnt lanes masked to row 0 + value-zeroed.
// Phase B: wave w computes output n-tile w: 8 MFMAs (mean@Wl + h@Wr), bias in acc.
// C/D layout: lane,reg -> out[mbase + (lane>>4)*4 + reg][nbase + (lane&15)]  [m89-verified]
template <bool RELU, bool BF16OUT>
__global__ __launch_bounds__(512) void k_conv(
    const int* __restrict__ cntArr, const int* __restrict__ slots,
    const ushort* __restrict__ h, const ushort* __restrict__ Wlb,
    const float* __restrict__ bl, const ushort* __restrict__ Wrb,
    void* __restrict__ outp, int ntgt) {
  __shared__ ushort smean[16 * LDSPAD];
  int wave = threadIdx.x >> 6;
  int lane = threadIdx.x & 63;
  int grp = lane >> 5, sub = lane & 31;
  int mbase = blockIdx.x * 16;
  int nl = wave * 2 + grp;
  int node = mbase + nl;

  // ---- Phase A ----
  int truecnt = (node < ntgt) ? cntArr[node] : 0;
  int cnt = min(truecnt, CAP);
  const int* sl = slots + (size_t)(node < ntgt ? node : 0) * CAP;
  int ev = (sub < cnt) ? sl[sub] : 0;
  int ev2 = (sub + 32 < cnt) ? sl[sub + 32] : 0;
  int dmax = max(cnt, __shfl_xor(cnt, 32, 64));
  int half = grp * 32;
  float s0 = 0.f, s1 = 0.f, s2 = 0.f, s3 = 0.f;
  for (int d = 0; d < dmax; d += 4) {
#pragma unroll
    for (int k = 0; k < 4; ++k) {
      int dk = d + k;
      int e = (dk < 32) ? __shfl(ev, half + dk, 64) : __shfl(ev2, half + dk - 32, 64);
      uint2 u = ((const uint2*)(h + (size_t)e * C))[sub];
      uint msk = (dk < cnt) ? 0xffffffffu : 0u;
      u.x &= msk; u.y &= msk;
      s0 += bf_lo(u.x); s1 += bf_hi(u.x); s2 += bf_lo(u.y); s3 += bf_hi(u.y);
    }
  }
  float sc = 1.f / (float)max(truecnt, 1);
  ushort4 o = {(ushort)f2bf(s0 * sc), (ushort)f2bf(s1 * sc),
               (ushort)f2bf(s2 * sc), (ushort)f2bf(s3 * sc)};
  *(ushort4*)(smean + nl * LDSPAD + sub * 4) = o;
  __syncthreads();

  // ---- Phase B ----
  int r16 = lane & 15;
  int quad = lane >> 4;
  int koff = quad * 8;
  bf16x8 am[4], ah[4];
  int hr = min(mbase + r16, ntgt - 1);
  const ushort* hrow = h + (size_t)hr * C;
#pragma unroll
  for (int kc = 0; kc < 4; ++kc) {
    am[kc] = *(const bf16x8*)(smean + r16 * LDSPAD + kc * 32 + koff);
    ah[kc] = *(const bf16x8*)(hrow + kc * 32 + koff);
  }
  int nbase = wave * 16;
  float bias = bl[nbase + r16];
  f32x4 acc = {bias, bias, bias, bias};
  const ushort* wlrow = Wlb + (size_t)(nbase + r16) * C;
  const ushort* wrrow = Wrb + (size_t)(nbase + r16) * C;
#pragma unroll
  for (int kc = 0; kc < 4; ++kc) {
    bf16x8 wl = *(const bf16x8*)(wlrow + kc * 32 + koff);
    acc = __builtin_amdgcn_mfma_f32_16x16x32_bf16(am[kc], wl, acc, 0, 0, 0);
    bf16x8 wr = *(const bf16x8*)(wrrow + kc * 32 + koff);
    acc = __builtin_amdgcn_mfma_f32_16x16x32_bf16(ah[kc], wr, acc, 0, 0, 0);
  }
#pragma unroll
  for (int r = 0; r < 4; ++r) {
    int row = mbase + quad * 4 + r;
    if (row < ntgt) {
      float v = acc[r];
      if (RELU) v = fmaxf(v, 0.f);
      if (BF16OUT)
        ((ushort*)outp)[(size_t)row * C + nbase + r16] = (ushort)f2bf(v);
      else
        ((float*)outp)[(size_t)row * C + nbase + r16] = v;
    }
  }
}

extern "C" void kernel_launch(void* const* d_in, const int* in_sizes, int n_in,
                              void* d_out, int out_size, void* d_ws, size_t ws_size,
                              hipStream_t stream) {
  const int*   x    = (const int*)d_in[0];
  const int*   src1 = (const int*)d_in[1];
  const int*   dst1 = (const int*)d_in[2];
  const int*   src2 = (const int*)d_in[3];
  const int*   dst2 = (const int*)d_in[4];
  const float* emb  = (const float*)d_in[7];
  const float* ln_g = (const float*)d_in[8];
  const float* ln_b = (const float*)d_in[9];
  const float* Wl1  = (const float*)d_in[10];
  const float* bl1  = (const float*)d_in[11];
  const float* Wr1  = (const float*)d_in[12];
  const float* Wl2  = (const float*)d_in[13];
  const float* bl2  = (const float*)d_in[14];
  const float* Wr2  = (const float*)d_in[15];

  const int N0 = in_sizes[0] / 16;   // 100000
  const int E1 = in_sizes[1];        // 500000
  const int E2 = in_sizes[3];        // 100000
  const int N1 = 25000;
  const int N2 = 5000;
  const int LEAF_ELEMS = in_sizes[7];  // 50000*128
  const int W_ELEMS = C * C;

  char* ws = (char*)d_ws;
  size_t off = 0;
  auto alloc = [&](size_t bytes) {
    char* p = ws + off;
    off += (bytes + 255) & ~(size_t)255;
    return p;
  };
  ushort* embh   = (ushort*)alloc((size_t)LEAF_ELEMS * 2);   // 12.8 MB
  ushort* h0     = (ushort*)alloc((size_t)N0 * C * 2);       // 25.6 MB
  ushort* h1     = (ushort*)alloc((size_t)N1 * C * 2);       //  6.4 MB
  ushort* wb     = (ushort*)alloc((size_t)4 * W_ELEMS * 2);  // Wl1|Wr1|Wl2|Wr2
  int*    slots1 = (int*)alloc((size_t)N1 * CAP * 4);        //  6.4 MB
  int*    slots2 = (int*)alloc((size_t)N2 * CAP * 4);        //  1.28 MB
  char*   zbase  = ws + off;  // zeroed by k_prep
  int*    cnt1   = (int*)alloc((size_t)N1 * 4);
  int*    cnt2   = (int*)alloc((size_t)N2 * 4);
  size_t  zbytes = (size_t)((ws + off) - zbase);

  float* out = (float*)d_out;
  ushort* Wl1b = wb;
  ushort* Wr1b = wb + W_ELEMS;
  ushort* Wl2b = wb + 2 * W_ELEMS;
  ushort* Wr2b = wb + 3 * W_ELEMS;

  // 1) prep: converts + cnt zeroing
  {
    int n4 = LEAF_ELEMS / 4;
    int nw4each = W_ELEMS / 4;
    int nz4 = (int)(zbytes / 16);
    k_prep<<<(n4 + 255) / 256, 256, 0, stream>>>(
        (const float4*)emb, (ushort4*)embh, n4,
        (const float4*)Wl1, (const float4*)Wr1, (const float4*)Wl2, (const float4*)Wr2,
        (ushort4*)wb, nw4each, (int4*)zbase, nz4);
  }

  // 2) padded-CSR bucket (both graphs)
  k_bucket2<<<(E1 + E2 + 255) / 256, 256, 0, stream>>>(
      src1, dst1, cnt1, slots1, E1, src2, dst2, cnt2, slots2, E2);

  // 3) embedding + LN + ReLU -> h0 bf16
  k_embed<<<(N0 + 3) / 4, 256, 0, stream>>>(x, embh, ln_g, ln_b, h0, N0);

  // 4) conv1 (aggregate + MFMA combine + ReLU) -> h1 bf16
  k_conv<true, true><<<(N1 + 15) / 16, 512, 0, stream>>>(
      cnt1, slots1, h0, Wl1b, bl1, Wr1b, h1, N1);

  // 5) conv2 -> d_out fp32
  k_conv<false, false><<<(N2 + 15) / 16, 512, 0, stream>>>(
      cnt2, slots2, h1, Wl2b, bl2, Wr2b, out, N2);
}

// Round 7
// 230.885 us; speedup vs baseline: 5.7429x; 1.0098x over previous
//
#include <hip/hip_runtime.h>

#define C 128
#define LDSPAD 136  // padded LDS row stride (ushorts); 2-way bank aliasing is free
#define CAP 64      // padded-CSR slots per node (mean deg 20, Poisson tail < 1e-13)

typedef unsigned int uint;
typedef unsigned short ushort;
typedef __attribute__((ext_vector_type(8))) short bf16x8;
typedef __attribute__((ext_vector_type(4))) float f32x4;

__device__ __forceinline__ float bf_lo(uint u) { return __uint_as_float(u << 16); }
__device__ __forceinline__ float bf_hi(uint u) { return __uint_as_float(u & 0xffff0000u); }
__device__ __forceinline__ uint f2bf(float f) {
  uint u = __float_as_uint(f);
  return (u + 0x7fffu + ((u >> 16) & 1u)) >> 16;  // RNE, no NaN inputs
}

// ---------------- Kernel 1: prep — emb->bf16, 4 weights->bf16, zero cnt arrays ----------------
__global__ __launch_bounds__(256) void k_prep(
    const float4* __restrict__ emb, ushort4* __restrict__ embh, int n4,
    const float4* __restrict__ w0, const float4* __restrict__ w1,
    const float4* __restrict__ w2, const float4* __restrict__ w3,
    ushort4* __restrict__ wb, int nw4each,
    int4* __restrict__ zb, int nz4) {
  int i = blockIdx.x * blockDim.x + threadIdx.x;
  if (i < n4) {
    float4 f = emb[i];
    ushort4 o = {(ushort)f2bf(f.x), (ushort)f2bf(f.y), (ushort)f2bf(f.z), (ushort)f2bf(f.w)};
    embh[i] = o;
  }
  if (i < 4 * nw4each) {
    int m = i / nw4each;
    int j = i - m * nw4each;
    const float4* w = (m == 0) ? w0 : (m == 1) ? w1 : (m == 2) ? w2 : w3;
    float4 f = w[j];
    ushort4 o = {(ushort)f2bf(f.x), (ushort)f2bf(f.y), (ushort)f2bf(f.z), (ushort)f2bf(f.w)};
    wb[i] = o;
  }
  if (i < nz4) {
    int4 z = {0, 0, 0, 0};
    zb[i] = z;
  }
}

// ---------------- Kernel 2: embed+LN+ReLU, with padded-CSR bucket in a separate block range ----
// blocks [0, bucketBlocks): bucket both edge lists (overlaps embed's memory waits).
// blocks [bucketBlocks, ...): one wave per node embedding-bag.
__global__ __launch_bounds__(256) void k_embed_bucket(
    const int* __restrict__ x, const ushort* __restrict__ emb,
    const float* __restrict__ g, const float* __restrict__ b,
    ushort* __restrict__ h, int n0,
    const int* __restrict__ src1, const int* __restrict__ dst1,
    int* __restrict__ cnt1, int* __restrict__ slots1, int e1,
    const int* __restrict__ src2, const int* __restrict__ dst2,
    int* __restrict__ cnt2, int* __restrict__ slots2, int e2,
    int bucketBlocks) {
  if (blockIdx.x < bucketBlocks) {
    int i = blockIdx.x * blockDim.x + threadIdx.x;
    if (i < e1) {
      int d = dst1[i];
      int p = atomicAdd(&cnt1[d], 1);
      if (p < CAP) slots1[d * CAP + p] = src1[i];
    } else if (i < e1 + e2) {
      int j = i - e1;
      int d = dst2[j];
      int p = atomicAdd(&cnt2[d], 1);
      if (p < CAP) slots2[d * CAP + p] = src2[j];
    }
    return;
  }
  int node = (blockIdx.x - bucketBlocks) * 4 + (threadIdx.x >> 6);
  int lane = threadIdx.x & 63;
  if (node >= n0) return;
  int grp = lane >> 5, sub = lane & 31;
  int xv = x[(size_t)node * 16 + (lane & 15)];
  float s0 = 0.f, s1 = 0.f, s2 = 0.f, s3 = 0.f;
#pragma unroll
  for (int w = 0; w < 16; w += 2) {
    int tok = __shfl(xv, w + grp, 64);
    uint2 u = ((const uint2*)(emb + (size_t)tok * C))[sub];
    s0 += bf_lo(u.x); s1 += bf_hi(u.x); s2 += bf_lo(u.y); s3 += bf_hi(u.y);
  }
  s0 += __shfl_xor(s0, 32, 64);
  s1 += __shfl_xor(s1, 32, 64);
  s2 += __shfl_xor(s2, 32, 64);
  s3 += __shfl_xor(s3, 32, 64);
  float red = s0 + s1 + s2 + s3;
#pragma unroll
  for (int off = 16; off; off >>= 1) red += __shfl_xor(red, off, 64);
  float mu = red * (1.f / C);
  float c0 = s0 - mu, c1 = s1 - mu, c2 = s2 - mu, c3 = s3 - mu;
  float sq = c0 * c0 + c1 * c1 + c2 * c2 + c3 * c3;
#pragma unroll
  for (int off = 16; off; off >>= 1) sq += __shfl_xor(sq, off, 64);
  float rs = rsqrtf(sq * (1.f / C) + 1e-5f);
  float4 gg = ((const float4*)g)[sub];
  float4 bb = ((const float4*)b)[sub];
  float o0 = fmaxf(c0 * rs * gg.x + bb.x, 0.f);
  float o1 = fmaxf(c1 * rs * gg.y + bb.y, 0.f);
  float o2 = fmaxf(c2 * rs * gg.z + bb.z, 0.f);
  float o3 = fmaxf(c3 * rs * gg.w + bb.w, 0.f);
  if (grp == 0) {
    ushort4 o = {(ushort)f2bf(o0), (ushort)f2bf(o1), (ushort)f2bf(o2), (ushort)f2bf(o3)};
    ((ushort4*)(h + (size_t)node * C))[sub] = o;
  }
}

// ---------------- Kernel 3/4: fused conv = aggregate(mean) + MFMA combine ----------------
// block = 512 (8 waves) -> 16 target nodes.
// Phase A: each HALF-wave aggregates one node; edge ids in registers (<=64 via CAP);
//          8 row-gathers in flight per half-wave.
// Phase B: wave w computes output n-tile w: 8 MFMAs (mean@Wl + h@Wr), bias in acc.
// C/D layout: lane,reg -> out[mbase + (lane>>4)*4 + reg][nbase + (lane&15)]  [m89-verified]
template <bool RELU, bool BF16OUT>
__global__ __launch_bounds__(512) void k_conv(
    const int* __restrict__ cntArr, const int* __restrict__ slots,
    const ushort* __restrict__ h, const ushort* __restrict__ Wlb,
    const float* __restrict__ bl, const ushort* __restrict__ Wrb,
    void* __restrict__ outp, int ntgt) {
  __shared__ ushort smean[16 * LDSPAD];
  int wave = threadIdx.x >> 6;
  int lane = threadIdx.x & 63;
  int grp = lane >> 5, sub = lane & 31;
  int mbase = blockIdx.x * 16;
  int nl = wave * 2 + grp;
  int node = mbase + nl;

  // ---- Phase A ----
  int truecnt = (node < ntgt) ? cntArr[node] : 0;
  int cnt = min(truecnt, CAP);
  const int* sl = slots + (size_t)(node < ntgt ? node : 0) * CAP;
  int ev = (sub < cnt) ? sl[sub] : 0;
  int ev2 = (sub + 32 < cnt) ? sl[sub + 32] : 0;
  int dmax = max(cnt, __shfl_xor(cnt, 32, 64));
  int half = grp * 32;
  float s0 = 0.f, s1 = 0.f, s2 = 0.f, s3 = 0.f;
  for (int d = 0; d < dmax; d += 8) {
#pragma unroll
    for (int k = 0; k < 8; ++k) {
      int dk = d + k;
      int e = (dk < 32) ? __shfl(ev, half + dk, 64) : __shfl(ev2, half + dk - 32, 64);
      uint2 u = ((const uint2*)(h + (size_t)e * C))[sub];
      uint msk = (dk < cnt) ? 0xffffffffu : 0u;
      u.x &= msk; u.y &= msk;
      s0 += bf_lo(u.x); s1 += bf_hi(u.x); s2 += bf_lo(u.y); s3 += bf_hi(u.y);
    }
  }
  float sc = 1.f / (float)max(truecnt, 1);
  ushort4 o = {(ushort)f2bf(s0 * sc), (ushort)f2bf(s1 * sc),
               (ushort)f2bf(s2 * sc), (ushort)f2bf(s3 * sc)};
  *(ushort4*)(smean + nl * LDSPAD + sub * 4) = o;
  __syncthreads();

  // ---- Phase B ----
  int r16 = lane & 15;
  int quad = lane >> 4;
  int koff = quad * 8;
  bf16x8 am[4], ah[4];
  int hr = min(mbase + r16, ntgt - 1);
  const ushort* hrow = h + (size_t)hr * C;
#pragma unroll
  for (int kc = 0; kc < 4; ++kc) {
    am[kc] = *(const bf16x8*)(smean + r16 * LDSPAD + kc * 32 + koff);
    ah[kc] = *(const bf16x8*)(hrow + kc * 32 + koff);
  }
  int nbase = wave * 16;
  float bias = bl[nbase + r16];
  f32x4 acc = {bias, bias, bias, bias};
  const ushort* wlrow = Wlb + (size_t)(nbase + r16) * C;
  const ushort* wrrow = Wrb + (size_t)(nbase + r16) * C;
#pragma unroll
  for (int kc = 0; kc < 4; ++kc) {
    bf16x8 wl = *(const bf16x8*)(wlrow + kc * 32 + koff);
    acc = __builtin_amdgcn_mfma_f32_16x16x32_bf16(am[kc], wl, acc, 0, 0, 0);
    bf16x8 wr = *(const bf16x8*)(wrrow + kc * 32 + koff);
    acc = __builtin_amdgcn_mfma_f32_16x16x32_bf16(ah[kc], wr, acc, 0, 0, 0);
  }
#pragma unroll
  for (int r = 0; r < 4; ++r) {
    int row = mbase + quad * 4 + r;
    if (row < ntgt) {
      float v = acc[r];
      if (RELU) v = fmaxf(v, 0.f);
      if (BF16OUT)
        ((ushort*)outp)[(size_t)row * C + nbase + r16] = (ushort)f2bf(v);
      else
        ((float*)outp)[(size_t)row * C + nbase + r16] = v;
    }
  }
}

extern "C" void kernel_launch(void* const* d_in, const int* in_sizes, int n_in,
                              void* d_out, int out_size, void* d_ws, size_t ws_size,
                              hipStream_t stream) {
  const int*   x    = (const int*)d_in[0];
  const int*   src1 = (const int*)d_in[1];
  const int*   dst1 = (const int*)d_in[2];
  const int*   src2 = (const int*)d_in[3];
  const int*   dst2 = (const int*)d_in[4];
  const float* emb  = (const float*)d_in[7];
  const float* ln_g = (const float*)d_in[8];
  const float* ln_b = (const float*)d_in[9];
  const float* Wl1  = (const float*)d_in[10];
  const float* bl1  = (const float*)d_in[11];
  const float* Wr1  = (const float*)d_in[12];
  const float* Wl2  = (const float*)d_in[13];
  const float* bl2  = (const float*)d_in[14];
  const float* Wr2  = (const float*)d_in[15];

  const int N0 = in_sizes[0] / 16;   // 100000
  const int E1 = in_sizes[1];        // 500000
  const int E2 = in_sizes[3];        // 100000
  const int N1 = 25000;
  const int N2 = 5000;
  const int LEAF_ELEMS = in_sizes[7];  // 50000*128
  const int W_ELEMS = C * C;

  char* ws = (char*)d_ws;
  size_t off = 0;
  auto alloc = [&](size_t bytes) {
    char* p = ws + off;
    off += (bytes + 255) & ~(size_t)255;
    return p;
  };
  ushort* embh   = (ushort*)alloc((size_t)LEAF_ELEMS * 2);   // 12.8 MB
  ushort* h0     = (ushort*)alloc((size_t)N0 * C * 2);       // 25.6 MB
  ushort* h1     = (ushort*)alloc((size_t)N1 * C * 2);       //  6.4 MB
  ushort* wb     = (ushort*)alloc((size_t)4 * W_ELEMS * 2);  // Wl1|Wr1|Wl2|Wr2
  int*    slots1 = (int*)alloc((size_t)N1 * CAP * 4);        //  6.4 MB
  int*    slots2 = (int*)alloc((size_t)N2 * CAP * 4);        //  1.28 MB
  char*   zbase  = ws + off;  // zeroed by k_prep
  int*    cnt1   = (int*)alloc((size_t)N1 * 4);
  int*    cnt2   = (int*)alloc((size_t)N2 * 4);
  size_t  zbytes = (size_t)((ws + off) - zbase);

  float* out = (float*)d_out;
  ushort* Wl1b = wb;
  ushort* Wr1b = wb + W_ELEMS;
  ushort* Wl2b = wb + 2 * W_ELEMS;
  ushort* Wr2b = wb + 3 * W_ELEMS;

  // 1) prep: converts + cnt zeroing
  {
    int n4 = LEAF_ELEMS / 4;
    int nw4each = W_ELEMS / 4;
    int nz4 = (int)(zbytes / 16);
    k_prep<<<(n4 + 255) / 256, 256, 0, stream>>>(
        (const float4*)emb, (ushort4*)embh, n4,
        (const float4*)Wl1, (const float4*)Wr1, (const float4*)Wl2, (const float4*)Wr2,
        (ushort4*)wb, nw4each, (int4*)zbase, nz4);
  }

  // 2) embed + LN + ReLU (+ bucket blocks first, overlapped)
  {
    int bucketBlocks = (E1 + E2 + 255) / 256;  // 2344
    int embBlocks = (N0 + 3) / 4;              // 25000
    k_embed_bucket<<<bucketBlocks + embBlocks, 256, 0, stream>>>(
        x, embh, ln_g, ln_b, h0, N0,
        src1, dst1, cnt1, slots1, E1,
        src2, dst2, cnt2, slots2, E2, bucketBlocks);
  }

  // 3) conv1 (aggregate + MFMA combine + ReLU) -> h1 bf16
  k_conv<true, true><<<(N1 + 15) / 16, 512, 0, stream>>>(
      cnt1, slots1, h0, Wl1b, bl1, Wr1b, h1, N1);

  // 4) conv2 -> d_out fp32
  k_conv<false, false><<<(N2 + 15) / 16, 512, 0, stream>>>(
      cnt2, slots2, h1, Wl2b, bl2, Wr2b, out, N2);
}